// Round 9
// baseline (710.664 us; speedup 1.0000x reference)
//
#include <hip/hip_runtime.h>

// ---------------------------------------------------------------------------
// MultiModalRelationGraph — R9  (R7 GEMM + barrier-free pipelined agg)
// - GEMM (R7): BK=64 ping-pong LDS A via global_load_lds(16B), fragment-packed
//   B global->VGPR, XCD swizzle, XOR LDS swizzle. ~860 TF (m97-family plateau).
// - Agg: alphas are PER-WAVE (wave w = head w) -> wredx butterfly + per-lane
//   redundant softmax: no LDS, no barriers in the !MEAN paths (R8 lesson: the
//   LDS+2-barrier dance per t exposed serial latency, VALU 20%/HBM 8%).
// - Region strips of 4 t's with REGISTER software pipeline: next-t rows
//   prefetched as raw ushort4 (bf2f deferred so vmcnt waits after a full
//   iteration of compute); hv(t)->hp(t+1) and ss(t)->ssPrev(t+1) in registers.
// - Layer 2 fuses head-mean + LayerNorm + chunk pooling (atomicAdd into
//   pre-zeroed d_out, scaled 1/3072 at the end).
// Node layout: region i in [i*8192,(i+1)*8192), node = i*8192 + b*512 + t.
// Audio: 32768 + b*1024 + ta.  Pool chunk = node_id / 3072.
// ---------------------------------------------------------------------------

typedef unsigned short u16;
typedef unsigned int u32;
typedef __bf16 bf16x8 __attribute__((ext_vector_type(8)));
typedef float f32x4 __attribute__((ext_vector_type(4)));

#define ASYNC16(gp, lp)                                                        \
  __builtin_amdgcn_global_load_lds(                                            \
      (const __attribute__((address_space(1))) void*)(gp),                     \
      (__attribute__((address_space(3))) void*)(lp), 16, 0, 0)

__device__ __forceinline__ u16 f2bf(float f) {
  union { float f; u32 u; } v; v.f = f;
  u32 u = v.u + 0x7FFFu + ((v.u >> 16) & 1u);  // RNE
  return (u16)(u >> 16);
}
__device__ __forceinline__ float bf2f(u16 x) {
  union { u32 u; float f; } v; v.u = ((u32)x) << 16;
  return v.f;
}
__device__ __forceinline__ float4 cvt4(ushort4 s) {
  float4 r; r.x = bf2f(s.x); r.y = bf2f(s.y); r.z = bf2f(s.z); r.w = bf2f(s.w);
  return r;
}
__device__ __forceinline__ float4 load_bf4(const u16* p) {
  return cvt4(*(const ushort4*)p);
}
__device__ __forceinline__ float lrelu(float v) { return v > 0.f ? v : 0.2f * v; }
__device__ __forceinline__ float dot4(float4 a, float4 b) {
  return a.x * b.x + a.y * b.y + a.z * b.z + a.w * b.w;
}
__device__ __forceinline__ float wredx(float v) {  // all lanes valid
#pragma unroll
  for (int off = 32; off; off >>= 1) v += __shfl_xor(v, off);
  return v;
}

// ---------------- weight pack: W [K][N] fp32 -> MFMA B-fragment order -------
struct PK { const float* W[8]; u16* P[8]; int KB[8]; int NN[8]; int st[9]; };
__global__ __launch_bounds__(256) void pack_kernel(PK p) {
  const int f = blockIdx.x * 4 + (threadIdx.x >> 6);
  const int lane = threadIdx.x & 63;
  int e = 0;
  while (f >= p.st[e + 1]) ++e;
  const int local = f - p.st[e];
  const int KB = p.KB[e], N = p.NN[e];
  const int nt = local / KB, kb = local % KB;
  const float* W = p.W[e] + (size_t)(kb * 32 + (lane >> 4) * 8) * N + nt * 16 + (lane & 15);
  u16* dst = p.P[e] + ((size_t)local * 64 + lane) * 8;
  u16 o[8];
#pragma unroll
  for (int j = 0; j < 8; ++j) o[j] = f2bf(W[(size_t)j * N]);
  *(uint4*)dst = *(uint4*)o;
}

// ---------------- layer GEMM: C[M,N]=A[M,K]@W^T; BK=64 dbuf LDS A (R7) ------
__global__ __launch_bounds__(256) void gemm_kernel(
    const u16* __restrict__ A, const u16* __restrict__ Bp, u16* __restrict__ C,
    int K, int ldc) {
  __shared__ __align__(16) u16 As[2][2][128 * 32];
  const int KB = K >> 5;
  const int KB2 = K >> 6;
  const int w = blockIdx.y * 8 + blockIdx.x;
  const int xcd = w & 7, m = w >> 3;
  const int blockCol = (m & 7) * 128;
  const int blockRow = ((m >> 3) * 8 + xcd) * 128;
  const int tid = threadIdx.x;
  const int wave = tid >> 6, lane = tid & 63;
  const int wr = (wave >> 1) * 64, wc = (wave & 1) * 64;
  const int lr = lane & 15, lq = lane >> 4;
  const int sRow = wave * 16 + (lane >> 2);
  const int sGc = (lane & 3) ^ ((sRow >> 1) & 3);
  const size_t aOff0 = (size_t)(blockRow + sRow) * K + sGc * 8;
  const size_t aOff1 = aOff0 + (size_t)64 * K;
  const int ldsOff0 = wave * 512;
  const int ldsOff1 = 2048 + wave * 512;

  const u16* Bn[4];
#pragma unroll
  for (int ni = 0; ni < 4; ++ni)
    Bn[ni] = Bp + ((size_t)(((blockCol + wc) >> 4) + ni) * KB) * 512 + lane * 8;

  f32x4 acc[4][4] = {};

#pragma unroll
  for (int h = 0; h < 2; ++h) {
    ASYNC16(A + aOff0 + h * 32, As[0][h] + ldsOff0);
    ASYNC16(A + aOff1 + h * 32, As[0][h] + ldsOff1);
  }
  __syncthreads();

  for (int kb2 = 0; kb2 < KB2; ++kb2) {
    const int cb = kb2 & 1;
    if (kb2 + 1 < KB2) {
      const size_t k1 = (size_t)(kb2 + 1) * 64;
#pragma unroll
      for (int h = 0; h < 2; ++h) {
        ASYNC16(A + aOff0 + k1 + h * 32, As[cb ^ 1][h] + ldsOff0);
        ASYNC16(A + aOff1 + k1 + h * 32, As[cb ^ 1][h] + ldsOff1);
      }
    }
#pragma unroll
    for (int h = 0; h < 2; ++h) {
      const int kb = kb2 * 2 + h;
      const u16* cur = As[cb][h];
      bf16x8 bfr[4];
#pragma unroll
      for (int ni = 0; ni < 4; ++ni)
        bfr[ni] = *(const bf16x8*)(Bn[ni] + (size_t)kb * 512);
      bf16x8 af[4];
#pragma unroll
      for (int mi = 0; mi < 4; ++mi) {
        const int R = wr + mi * 16 + lr;
        const int cp = lq ^ ((R >> 1) & 3);
        af[mi] = *(const bf16x8*)(cur + R * 32 + cp * 8);
      }
#pragma unroll
      for (int mi = 0; mi < 4; ++mi)
#pragma unroll
        for (int ni = 0; ni < 4; ++ni)
          acc[mi][ni] = __builtin_amdgcn_mfma_f32_16x16x32_bf16(af[mi], bfr[ni],
                                                                acc[mi][ni], 0, 0, 0);
    }
    __syncthreads();
  }
#pragma unroll
  for (int mi = 0; mi < 4; ++mi)
#pragma unroll
    for (int ni = 0; ni < 4; ++ni) {
      const int col = blockCol + wc + ni * 16 + lr;
#pragma unroll
      for (int r = 0; r < 4; ++r) {
        const int row = blockRow + wr + mi * 16 + lq * 4 + r;
        C[(size_t)row * ldc + col] = f2bf(acc[mi][ni][r]);
      }
    }
}

// ---------------- fused input projection (fp32 A in-register cvt) -----------
struct ProjArgs { const float* x[5]; const u16* w[5]; const float* b[5]; };
__global__ __launch_bounds__(256) void proj_kernel(ProjArgs pa,
                                                   u16* __restrict__ C) {
  __shared__ __align__(16) u16 As[128 * 32];
  const int blockRow = blockIdx.y * 128, blockCol = blockIdx.x * 128;
  const int reg = blockRow >= 32768 ? 4 : (blockRow >> 13);
  const int regBase = reg == 4 ? 32768 : reg * 8192;
  const float* Af = pa.x[reg] + (size_t)(blockRow - regBase) * 512;
  const u16* Bp = pa.w[reg];
  const int tid = threadIdx.x;
  const int wave = tid >> 6, lane = tid & 63;
  const int wr = (wave >> 1) * 64, wc = (wave & 1) * 64;
  const int lr = lane & 15, lq = lane >> 4;
  const int rr = tid >> 2;
  const int cphys = tid & 3;
  const int sGc = cphys ^ ((tid >> 3) & 3);

  const u16* Bn[4];
#pragma unroll
  for (int ni = 0; ni < 4; ++ni)
    Bn[ni] = Bp + ((size_t)(((blockCol + wc) >> 4) + ni) * 16) * 512 + lane * 8;

  f32x4 acc[4][4] = {};

  for (int k0 = 0; k0 < 512; k0 += 32) {
    __syncthreads();
    bf16x8 bfr[4];
#pragma unroll
    for (int ni = 0; ni < 4; ++ni)
      bfr[ni] = *(const bf16x8*)(Bn[ni] + (size_t)k0 * 16);
#pragma unroll
    for (int i = 0; i < 2; ++i) {
      const int row = i * 64 + rr;
      const float* ap = Af + (size_t)row * 512 + k0 + sGc * 8;
      float4 f0 = *(const float4*)(ap);
      float4 f1 = *(const float4*)(ap + 4);
      uint4 pk;
      pk.x = (u32)f2bf(f0.x) | ((u32)f2bf(f0.y) << 16);
      pk.y = (u32)f2bf(f0.z) | ((u32)f2bf(f0.w) << 16);
      pk.z = (u32)f2bf(f1.x) | ((u32)f2bf(f1.y) << 16);
      pk.w = (u32)f2bf(f1.z) | ((u32)f2bf(f1.w) << 16);
      *(uint4*)(&As[row * 32 + cphys * 8]) = pk;
    }
    __syncthreads();
    bf16x8 af[4];
#pragma unroll
    for (int mi = 0; mi < 4; ++mi) {
      const int R = wr + mi * 16 + lr;
      const int cp = lq ^ ((R >> 1) & 3);
      af[mi] = *(const bf16x8*)(&As[R * 32 + cp * 8]);
    }
#pragma unroll
    for (int mi = 0; mi < 4; ++mi)
#pragma unroll
      for (int ni = 0; ni < 4; ++ni)
        acc[mi][ni] = __builtin_amdgcn_mfma_f32_16x16x32_bf16(af[mi], bfr[ni],
                                                              acc[mi][ni], 0, 0, 0);
  }
  const float* bias = pa.b[reg];
#pragma unroll
  for (int mi = 0; mi < 4; ++mi)
#pragma unroll
    for (int ni = 0; ni < 4; ++ni) {
      const int col = blockCol + wc + ni * 16 + lr;
      const float bv = bias[col];
#pragma unroll
      for (int r = 0; r < 4; ++r) {
        const int row = blockRow + wr + mi * 16 + lq * 4 + r;
        C[(size_t)row * 256 + col] = f2bf(acc[mi][ni][r] + bv);
      }
    }
}

// ---------------- aggregation: barrier-free alphas, pipelined strips --------
// Region (bid<2048): block = (b, 4-t strip). Wave w == head w: dots via wredx
// (all lanes), softmax per-lane redundant -> no LDS/barriers. Raw ushort4
// prefetch of t+1 rows; ss/hv carried to t+1 in registers.
// Audio (bid>=2048): even+odd node pair per block, barrier-free alphas.
// MEAN (layer 2): + head-mean/LN/pool via LDS (2 barriers per node-set).
template <bool MEAN>
__global__ __launch_bounds__(256) void agg_kernel(
    const u16* __restrict__ h, const float* __restrict__ a_s,
    const float* __restrict__ a_d, const float* __restrict__ bias,
    const float* __restrict__ lng, const float* __restrict__ lnb,
    void* __restrict__ out) {
  const int tid = threadIdx.x;
  const int head = tid >> 6;
  const int c4 = tid * 4;
  const float4 sa = *(const float4*)(a_s + c4);
  const float4 da = *(const float4*)(a_d + c4);

  if (blockIdx.x < 2048) {
    // ---- region strip: b = bid>>7, t in [t0, t0+4) ----
    const int b = blockIdx.x >> 7;
    const int t0 = (blockIdx.x & 127) * 4;
    const int btBase = b * 512 + t0;
    float4 hprev[4];
    float ssPrev[4] = {};
    if (t0 > 0) {
#pragma unroll
      for (int r = 0; r < 4; ++r)
        hprev[r] = load_bf4(h + (size_t)(r * 8192 + btBase - 1) * 1024 + c4);
#pragma unroll
      for (int r = 0; r < 4; ++r) ssPrev[r] = wredx(dot4(hprev[r], sa));
    }
    ushort4 rcur[4];
#pragma unroll
    for (int r = 0; r < 4; ++r)
      rcur[r] = *(const ushort4*)(h + (size_t)(r * 8192 + btBase) * 1024 + c4);

    float pacc[4] = {};
    int pch[4] = {-1, -1, -1, -1};

    for (int tt = 0; tt < 4; ++tt) {
      const int bt = btBase + tt;
      const bool hasPrev = (t0 + tt) > 0;
      ushort4 rnxt[4];
      if (tt < 3) {  // prefetch next t's rows (raw; cvt deferred)
#pragma unroll
        for (int r = 0; r < 4; ++r)
          rnxt[r] = *(const ushort4*)(h + (size_t)(r * 8192 + bt + 1) * 1024 + c4);
      }
      float4 hv[4];
#pragma unroll
      for (int r = 0; r < 4; ++r) hv[r] = cvt4(rcur[r]);
      float ss[4], dd[4];
#pragma unroll
      for (int r = 0; r < 4; ++r) {
        ss[r] = wredx(dot4(hv[r], sa));
        dd[r] = wredx(dot4(hv[r], da));
      }
      float4 av[4];  // per-dst aggregate for this lane's 4 channels
#pragma unroll
      for (int j = 0; j < 4; ++j) {
        const float ad = dd[j];
        float e0 = lrelu(ss[0] + ad), e1 = lrelu(ss[1] + ad);
        float e2 = lrelu(ss[2] + ad), e3 = lrelu(ss[3] + ad);
        float mx = fmaxf(fmaxf(e0, e1), fmaxf(e2, e3));
        float e4 = 0.f;
        if (hasPrev) { e4 = lrelu(ssPrev[j] + ad); mx = fmaxf(mx, e4); }
        const float x0 = __expf(e0 - mx), x1 = __expf(e1 - mx);
        const float x2 = __expf(e2 - mx), x3 = __expf(e3 - mx);
        const float x4 = hasPrev ? __expf(e4 - mx) : 0.f;
        const float inv = 1.f / (x0 + x1 + x2 + x3 + x4 + 1e-16f);
        const float a0 = x0 * inv, a1 = x1 * inv, a2 = x2 * inv, a3 = x3 * inv;
        const float a4 = x4 * inv;
        float4 acc;
        acc.x = a0 * hv[0].x + a1 * hv[1].x + a2 * hv[2].x + a3 * hv[3].x;
        acc.y = a0 * hv[0].y + a1 * hv[1].y + a2 * hv[2].y + a3 * hv[3].y;
        acc.z = a0 * hv[0].z + a1 * hv[1].z + a2 * hv[2].z + a3 * hv[3].z;
        acc.w = a0 * hv[0].w + a1 * hv[1].w + a2 * hv[2].w + a3 * hv[3].w;
        if (hasPrev) {
          acc.x += a4 * hprev[j].x; acc.y += a4 * hprev[j].y;
          acc.z += a4 * hprev[j].z; acc.w += a4 * hprev[j].w;
        }
        av[j] = acc;
      }
      if constexpr (!MEAN) {
        const float4 bv = *(const float4*)(bias + c4);
        u16* ob = (u16*)out;
#pragma unroll
        for (int j = 0; j < 4; ++j) {
          ushort4 o;
          o.x = f2bf(av[j].x + bv.x); o.y = f2bf(av[j].y + bv.y);
          o.z = f2bf(av[j].z + bv.z); o.w = f2bf(av[j].w + bv.w);
          *(ushort4*)(ob + (size_t)(j * 8192 + bt) * 1024 + c4) = o;
        }
      } else {
        __shared__ float red[4096];
        __shared__ float ls[32];
#pragma unroll
        for (int j = 0; j < 4; ++j) *(float4*)(&red[j * 1024 + c4]) = av[j];
        __syncthreads();
        const float bb = bias[tid];
        float v[4];
#pragma unroll
        for (int j = 0; j < 4; ++j) {
          v[j] = 0.25f * (red[j * 1024 + tid] + red[j * 1024 + tid + 256] +
                          red[j * 1024 + tid + 512] + red[j * 1024 + tid + 768]) + bb;
          const float sj = wredx(v[j]);
          const float qj = wredx(v[j] * v[j]);
          if ((tid & 63) == 0) { ls[head * 8 + j * 2] = sj; ls[head * 8 + j * 2 + 1] = qj; }
        }
        __syncthreads();
#pragma unroll
        for (int j = 0; j < 4; ++j) {
          const float S = ls[j * 2] + ls[8 + j * 2] + ls[16 + j * 2] + ls[24 + j * 2];
          const float Q = ls[j * 2 + 1] + ls[8 + j * 2 + 1] + ls[16 + j * 2 + 1] +
                          ls[24 + j * 2 + 1];
          const float mean = S * (1.f / 256.f);
          const float var = Q * (1.f / 256.f) - mean * mean;
          const float n = (v[j] - mean) * rsqrtf(var + 1e-5f) * lng[tid] + lnb[tid];
          const int ch = (j * 8192 + bt) / 3072;
          if (ch != pch[j]) {
            if (pch[j] >= 0) atomicAdd((float*)out + pch[j] * 256 + tid, pacc[j]);
            pacc[j] = 0.f; pch[j] = ch;
          }
          pacc[j] += n;
        }
      }
#pragma unroll
      for (int r = 0; r < 4; ++r) {
        hprev[r] = hv[r];
        ssPrev[r] = ss[r];
        rcur[r] = rnxt[r];
      }
    }
    if constexpr (MEAN) {
#pragma unroll
      for (int j = 0; j < 4; ++j)
        if (pch[j] >= 0) atomicAdd((float*)out + pch[j] * 256 + tid, pacc[j]);
    }
  } else {
    // ---- audio pair: nodes idx0 (even) + idx0+1 (odd) ----
    const int aid = blockIdx.x - 2048;
    const int idx0 = aid * 2;
    const int b = idx0 >> 10;
    const int ta0 = idx0 & 1023;
    const int n0 = 32768 + idx0, n1 = n0 + 1;
    const int tt2 = ta0 >> 1;
    const int le = 8192 + b * 512 + tt2;
    const int re = 16384 + b * 512 + tt2;
    float4 v0 = load_bf4(h + (size_t)n0 * 1024 + c4);
    float4 vo = load_bf4(h + (size_t)n1 * 1024 + c4);
    float4 v1 = load_bf4(h + (size_t)le * 1024 + c4);
    float4 v2 = load_bf4(h + (size_t)re * 1024 + c4);
    const float s0 = wredx(dot4(v0, sa));
    const float s1 = wredx(dot4(v1, sa));
    const float s2 = wredx(dot4(v2, sa));
    const float d0 = wredx(dot4(v0, da));
    {
      const float e0 = lrelu(s0 + d0), e1 = lrelu(s1 + d0), e2 = lrelu(s2 + d0);
      const float mx = fmaxf(e0, fmaxf(e1, e2));
      const float x0 = __expf(e0 - mx), x1 = __expf(e1 - mx), x2 = __expf(e2 - mx);
      const float inv = 1.f / (x0 + x1 + x2 + 1e-16f);
      const float a0 = x0 * inv, a1 = x1 * inv, a2 = x2 * inv;
      v0.x = a0 * v0.x + a1 * v1.x + a2 * v2.x;
      v0.y = a0 * v0.y + a1 * v1.y + a2 * v2.y;
      v0.z = a0 * v0.z + a1 * v1.z + a2 * v2.z;
      v0.w = a0 * v0.w + a1 * v1.w + a2 * v2.w;
    }
    if constexpr (!MEAN) {
      const float4 bv = *(const float4*)(bias + c4);
      ushort4 oe, oo;
      oe.x = f2bf(v0.x + bv.x); oe.y = f2bf(v0.y + bv.y);
      oe.z = f2bf(v0.z + bv.z); oe.w = f2bf(v0.w + bv.w);
      oo.x = f2bf(vo.x + bv.x); oo.y = f2bf(vo.y + bv.y);
      oo.z = f2bf(vo.z + bv.z); oo.w = f2bf(vo.w + bv.w);
      *(ushort4*)((u16*)out + (size_t)n0 * 1024 + c4) = oe;
      *(ushort4*)((u16*)out + (size_t)n1 * 1024 + c4) = oo;
    } else {
      __shared__ float redA[2048];
      __shared__ float lsA[32];
      *(float4*)(&redA[c4]) = v0;
      *(float4*)(&redA[1024 + c4]) = vo;
      __syncthreads();
      const float bb = bias[tid];
      float vA = 0.25f * (redA[tid] + redA[tid + 256] + redA[tid + 512] +
                          redA[tid + 768]) + bb;
      float vB = 0.25f * (redA[1024 + tid] + redA[1024 + tid + 256] +
                          redA[1024 + tid + 512] + redA[1024 + tid + 768]) + bb;
      const float sA = wredx(vA), qA = wredx(vA * vA);
      const float sB = wredx(vB), qB = wredx(vB * vB);
      if ((tid & 63) == 0) {
        lsA[head * 8] = sA; lsA[head * 8 + 1] = qA;
        lsA[head * 8 + 2] = sB; lsA[head * 8 + 3] = qB;
      }
      __syncthreads();
      const float SA = lsA[0] + lsA[8] + lsA[16] + lsA[24];
      const float QA = lsA[1] + lsA[9] + lsA[17] + lsA[25];
      const float SB = lsA[2] + lsA[10] + lsA[18] + lsA[26];
      const float QB = lsA[3] + lsA[11] + lsA[19] + lsA[27];
      const float mA = SA * (1.f / 256.f), vrA = QA * (1.f / 256.f) - mA * mA;
      const float mB = SB * (1.f / 256.f), vrB = QB * (1.f / 256.f) - mB * mB;
      const float g = lng[tid], be = lnb[tid];
      const float nA = (vA - mA) * rsqrtf(vrA + 1e-5f) * g + be;
      const float nB = (vB - mB) * rsqrtf(vrB + 1e-5f) * g + be;
      const int ch0 = n0 / 3072, ch1 = n1 / 3072;
      if (ch0 == ch1) {
        atomicAdd((float*)out + ch0 * 256 + tid, nA + nB);
      } else {
        atomicAdd((float*)out + ch0 * 256 + tid, nA);
        atomicAdd((float*)out + ch1 * 256 + tid, nB);
      }
    }
  }
}

// ---------------- out-buffer zero + final scale ------------------------------
__global__ __launch_bounds__(256) void zero_kernel(float* __restrict__ p) {
  p[blockIdx.x * 256 + threadIdx.x] = 0.f;
}
__global__ __launch_bounds__(256) void scale_kernel(float* __restrict__ p) {
  const int i = blockIdx.x * 256 + threadIdx.x;
  p[i] *= (1.f / 3072.f);
}

// ---------------------------------------------------------------------------
extern "C" void kernel_launch(void* const* d_in, const int* in_sizes, int n_in,
                              void* d_out, int out_size, void* d_ws, size_t ws_size,
                              hipStream_t stream) {
  const float* x_reg[4] = {(const float*)d_in[0], (const float*)d_in[1],
                           (const float*)d_in[2], (const float*)d_in[3]};
  const float* audio = (const float*)d_in[4];
  const float* w_reg[4] = {(const float*)d_in[5], (const float*)d_in[7],
                           (const float*)d_in[9], (const float*)d_in[11]};
  const float* b_reg[4] = {(const float*)d_in[6], (const float*)d_in[8],
                           (const float*)d_in[10], (const float*)d_in[12]};
  const float* w_aud = (const float*)d_in[13];
  const float* b_aud = (const float*)d_in[14];
  const float* Wl[3] = {(const float*)d_in[15], (const float*)d_in[19],
                        (const float*)d_in[23]};
  const float* as_in[3] = {(const float*)d_in[16], (const float*)d_in[20],
                           (const float*)d_in[24]};
  const float* ad_in[3] = {(const float*)d_in[17], (const float*)d_in[21],
                           (const float*)d_in[25]};
  const float* bias_l[3] = {(const float*)d_in[18], (const float*)d_in[22],
                            (const float*)d_in[26]};
  const float* ln_g = (const float*)d_in[27];
  const float* ln_b = (const float*)d_in[28];

  // workspace layout (<200 MiB)
  char* ws = (char*)d_ws;
  u16* h_bf = (u16*)ws;                    // [N,1024] bf16 (96 MiB)
  u16* xb = (u16*)(ws + 100663296);        // [N,1024] bf16 x buffer
  u16* wt = (u16*)(ws + 201326592);        // packed bf16 weights (~6 MiB)

  u16* wtp[5];
  for (int r = 0; r < 5; ++r) wtp[r] = wt + (size_t)r * 131072;
  u16* wt0 = wt + 655360;   // 512 frags
  u16* wt1 = wt + 917504;   // 2048 frags
  u16* wt2 = wt + 1966080;  // 2048 frags

  // 1) pack all weights into MFMA fragment order; zero the pooling accumulator
  PK pk;
  for (int r = 0; r < 4; ++r) { pk.W[r] = w_reg[r]; pk.P[r] = wtp[r]; pk.KB[r] = 16; pk.NN[r] = 256; }
  pk.W[4] = w_aud; pk.P[4] = wtp[4]; pk.KB[4] = 16; pk.NN[4] = 256;
  pk.W[5] = Wl[0]; pk.P[5] = wt0; pk.KB[5] = 8;  pk.NN[5] = 1024;
  pk.W[6] = Wl[1]; pk.P[6] = wt1; pk.KB[6] = 32; pk.NN[6] = 1024;
  pk.W[7] = Wl[2]; pk.P[7] = wt2; pk.KB[7] = 32; pk.NN[7] = 1024;
  pk.st[0] = 0;
  {
    const int nfr[8] = {256, 256, 256, 256, 256, 512, 2048, 2048};
    int acc = 0;
    for (int e = 0; e < 8; ++e) { acc += nfr[e]; pk.st[e + 1] = acc; }
  }
  pack_kernel<<<pk.st[8] / 4, 256, 0, stream>>>(pk);
  zero_kernel<<<16, 256, 0, stream>>>((float*)d_out);

  // 2) fused input projections (fp32 in, bf16 out) -> x0 [N,256]
  ProjArgs pa;
  for (int r = 0; r < 4; ++r) { pa.x[r] = x_reg[r]; pa.w[r] = wtp[r]; pa.b[r] = b_reg[r]; }
  pa.x[4] = audio; pa.w[4] = wtp[4]; pa.b[4] = b_aud;
  proj_kernel<<<dim3(2, 384), 256, 0, stream>>>(pa, xb);

  // 3) three GAT layers: BK=64 dbuf gemm -> barrier-free pipelined agg
  const u16* wl[3] = {wt0, wt1, wt2};
  const int Kl[3] = {256, 1024, 1024};
  for (int l = 0; l < 3; ++l) {
    gemm_kernel<<<dim3(8, 384), 256, 0, stream>>>(xb, wl[l], h_bf, Kl[l], 1024);
    if (l < 2)
      agg_kernel<false><<<10240, 256, 0, stream>>>(h_bf, as_in[l], ad_in[l],
                                                   bias_l[l], nullptr, nullptr, xb);
    else
      agg_kernel<true><<<10240, 256, 0, stream>>>(h_bf, as_in[l], ad_in[l],
                                                  bias_l[l], ln_g, ln_b, d_out);
  }

  // 4) final scale: out = acc / 3072
  scale_kernel<<<16, 256, 0, stream>>>((float*)d_out);
}

// Round 10
// 690.009 us; speedup vs baseline: 1.0299x; 1.0299x over previous
//
#include <hip/hip_runtime.h>

// ---------------------------------------------------------------------------
// MultiModalRelationGraph — R10  (R7 GEMM + max-TLP barrier-free agg)
// - GEMM (R7): BK=64 ping-pong LDS A via global_load_lds(16B), fragment-packed
//   B global->VGPR, XCD swizzle, XOR LDS swizzle. ~860 TF (m97-family plateau).
// - Agg lesson ledger: R8 strip-8 (131us) and R9 strip-4 (152us) both lost to
//   R7's simple one-bt-per-block (~94us) — agg is L3-LATENCY-bound (h fits in
//   256MB L3; FETCH only ~70MB), so TLP is everything and strip-mining kills
//   it. R10 = max TLP (24576 blocks) + R9's barrier-free per-wave alphas
//   (wave w == head w -> wredx dots + per-lane redundant softmax; no LDS, no
//   barriers in !MEAN). Dynamic LDS so !MEAN allocates 0 B (R9 leaked 25KB
//   into both template instantiations).
// - Layer 2 (MEAN) fuses head-mean + LayerNorm + chunk pooling; atomicAdd
//   into [16][8][256] slotted partials (contention /8), final reduce+scale.
// Node layout: region i in [i*8192,(i+1)*8192), node = i*8192 + b*512 + t.
// Audio: 32768 + b*1024 + ta.  Pool chunk = node_id / 3072.
// ---------------------------------------------------------------------------

typedef unsigned short u16;
typedef unsigned int u32;
typedef __bf16 bf16x8 __attribute__((ext_vector_type(8)));
typedef float f32x4 __attribute__((ext_vector_type(4)));

#define ASYNC16(gp, lp)                                                        \
  __builtin_amdgcn_global_load_lds(                                            \
      (const __attribute__((address_space(1))) void*)(gp),                     \
      (__attribute__((address_space(3))) void*)(lp), 16, 0, 0)

__device__ __forceinline__ u16 f2bf(float f) {
  union { float f; u32 u; } v; v.f = f;
  u32 u = v.u + 0x7FFFu + ((v.u >> 16) & 1u);  // RNE
  return (u16)(u >> 16);
}
__device__ __forceinline__ float bf2f(u16 x) {
  union { u32 u; float f; } v; v.u = ((u32)x) << 16;
  return v.f;
}
__device__ __forceinline__ float4 cvt4(ushort4 s) {
  float4 r; r.x = bf2f(s.x); r.y = bf2f(s.y); r.z = bf2f(s.z); r.w = bf2f(s.w);
  return r;
}
__device__ __forceinline__ float lrelu(float v) { return v > 0.f ? v : 0.2f * v; }
__device__ __forceinline__ float dot4(float4 a, float4 b) {
  return a.x * b.x + a.y * b.y + a.z * b.z + a.w * b.w;
}
__device__ __forceinline__ float wredx(float v) {  // all lanes valid
#pragma unroll
  for (int off = 32; off; off >>= 1) v += __shfl_xor(v, off);
  return v;
}

// ---------------- weight pack: W [K][N] fp32 -> MFMA B-fragment order -------
struct PK { const float* W[8]; u16* P[8]; int KB[8]; int NN[8]; int st[9]; };
__global__ __launch_bounds__(256) void pack_kernel(PK p) {
  const int f = blockIdx.x * 4 + (threadIdx.x >> 6);
  const int lane = threadIdx.x & 63;
  int e = 0;
  while (f >= p.st[e + 1]) ++e;
  const int local = f - p.st[e];
  const int KB = p.KB[e], N = p.NN[e];
  const int nt = local / KB, kb = local % KB;
  const float* W = p.W[e] + (size_t)(kb * 32 + (lane >> 4) * 8) * N + nt * 16 + (lane & 15);
  u16* dst = p.P[e] + ((size_t)local * 64 + lane) * 8;
  u16 o[8];
#pragma unroll
  for (int j = 0; j < 8; ++j) o[j] = f2bf(W[(size_t)j * N]);
  *(uint4*)dst = *(uint4*)o;
}

// ---------------- layer GEMM: C[M,N]=A[M,K]@W^T; BK=64 dbuf LDS A (R7) ------
__global__ __launch_bounds__(256) void gemm_kernel(
    const u16* __restrict__ A, const u16* __restrict__ Bp, u16* __restrict__ C,
    int K, int ldc) {
  __shared__ __align__(16) u16 As[2][2][128 * 32];
  const int KB = K >> 5;
  const int KB2 = K >> 6;
  const int w = blockIdx.y * 8 + blockIdx.x;
  const int xcd = w & 7, m = w >> 3;
  const int blockCol = (m & 7) * 128;
  const int blockRow = ((m >> 3) * 8 + xcd) * 128;
  const int tid = threadIdx.x;
  const int wave = tid >> 6, lane = tid & 63;
  const int wr = (wave >> 1) * 64, wc = (wave & 1) * 64;
  const int lr = lane & 15, lq = lane >> 4;
  const int sRow = wave * 16 + (lane >> 2);
  const int sGc = (lane & 3) ^ ((sRow >> 1) & 3);
  const size_t aOff0 = (size_t)(blockRow + sRow) * K + sGc * 8;
  const size_t aOff1 = aOff0 + (size_t)64 * K;
  const int ldsOff0 = wave * 512;
  const int ldsOff1 = 2048 + wave * 512;

  const u16* Bn[4];
#pragma unroll
  for (int ni = 0; ni < 4; ++ni)
    Bn[ni] = Bp + ((size_t)(((blockCol + wc) >> 4) + ni) * KB) * 512 + lane * 8;

  f32x4 acc[4][4] = {};

#pragma unroll
  for (int h = 0; h < 2; ++h) {
    ASYNC16(A + aOff0 + h * 32, As[0][h] + ldsOff0);
    ASYNC16(A + aOff1 + h * 32, As[0][h] + ldsOff1);
  }
  __syncthreads();

  for (int kb2 = 0; kb2 < KB2; ++kb2) {
    const int cb = kb2 & 1;
    if (kb2 + 1 < KB2) {
      const size_t k1 = (size_t)(kb2 + 1) * 64;
#pragma unroll
      for (int h = 0; h < 2; ++h) {
        ASYNC16(A + aOff0 + k1 + h * 32, As[cb ^ 1][h] + ldsOff0);
        ASYNC16(A + aOff1 + k1 + h * 32, As[cb ^ 1][h] + ldsOff1);
      }
    }
#pragma unroll
    for (int h = 0; h < 2; ++h) {
      const int kb = kb2 * 2 + h;
      const u16* cur = As[cb][h];
      bf16x8 bfr[4];
#pragma unroll
      for (int ni = 0; ni < 4; ++ni)
        bfr[ni] = *(const bf16x8*)(Bn[ni] + (size_t)kb * 512);
      bf16x8 af[4];
#pragma unroll
      for (int mi = 0; mi < 4; ++mi) {
        const int R = wr + mi * 16 + lr;
        const int cp = lq ^ ((R >> 1) & 3);
        af[mi] = *(const bf16x8*)(cur + R * 32 + cp * 8);
      }
#pragma unroll
      for (int mi = 0; mi < 4; ++mi)
#pragma unroll
        for (int ni = 0; ni < 4; ++ni)
          acc[mi][ni] = __builtin_amdgcn_mfma_f32_16x16x32_bf16(af[mi], bfr[ni],
                                                                acc[mi][ni], 0, 0, 0);
    }
    __syncthreads();
  }
#pragma unroll
  for (int mi = 0; mi < 4; ++mi)
#pragma unroll
    for (int ni = 0; ni < 4; ++ni) {
      const int col = blockCol + wc + ni * 16 + lr;
#pragma unroll
      for (int r = 0; r < 4; ++r) {
        const int row = blockRow + wr + mi * 16 + lq * 4 + r;
        C[(size_t)row * ldc + col] = f2bf(acc[mi][ni][r]);
      }
    }
}

// ---------------- fused input projection (fp32 A in-register cvt) -----------
struct ProjArgs { const float* x[5]; const u16* w[5]; const float* b[5]; };
__global__ __launch_bounds__(256) void proj_kernel(ProjArgs pa,
                                                   u16* __restrict__ C) {
  __shared__ __align__(16) u16 As[128 * 32];
  const int blockRow = blockIdx.y * 128, blockCol = blockIdx.x * 128;
  const int reg = blockRow >= 32768 ? 4 : (blockRow >> 13);
  const int regBase = reg == 4 ? 32768 : reg * 8192;
  const float* Af = pa.x[reg] + (size_t)(blockRow - regBase) * 512;
  const u16* Bp = pa.w[reg];
  const int tid = threadIdx.x;
  const int wave = tid >> 6, lane = tid & 63;
  const int wr = (wave >> 1) * 64, wc = (wave & 1) * 64;
  const int lr = lane & 15, lq = lane >> 4;
  const int rr = tid >> 2;
  const int cphys = tid & 3;
  const int sGc = cphys ^ ((tid >> 3) & 3);

  const u16* Bn[4];
#pragma unroll
  for (int ni = 0; ni < 4; ++ni)
    Bn[ni] = Bp + ((size_t)(((blockCol + wc) >> 4) + ni) * 16) * 512 + lane * 8;

  f32x4 acc[4][4] = {};

  for (int k0 = 0; k0 < 512; k0 += 32) {
    __syncthreads();
    bf16x8 bfr[4];
#pragma unroll
    for (int ni = 0; ni < 4; ++ni)
      bfr[ni] = *(const bf16x8*)(Bn[ni] + (size_t)k0 * 16);
#pragma unroll
    for (int i = 0; i < 2; ++i) {
      const int row = i * 64 + rr;
      const float* ap = Af + (size_t)row * 512 + k0 + sGc * 8;
      float4 f0 = *(const float4*)(ap);
      float4 f1 = *(const float4*)(ap + 4);
      uint4 pk;
      pk.x = (u32)f2bf(f0.x) | ((u32)f2bf(f0.y) << 16);
      pk.y = (u32)f2bf(f0.z) | ((u32)f2bf(f0.w) << 16);
      pk.z = (u32)f2bf(f1.x) | ((u32)f2bf(f1.y) << 16);
      pk.w = (u32)f2bf(f1.z) | ((u32)f2bf(f1.w) << 16);
      *(uint4*)(&As[row * 32 + cphys * 8]) = pk;
    }
    __syncthreads();
    bf16x8 af[4];
#pragma unroll
    for (int mi = 0; mi < 4; ++mi) {
      const int R = wr + mi * 16 + lr;
      const int cp = lq ^ ((R >> 1) & 3);
      af[mi] = *(const bf16x8*)(&As[R * 32 + cp * 8]);
    }
#pragma unroll
    for (int mi = 0; mi < 4; ++mi)
#pragma unroll
      for (int ni = 0; ni < 4; ++ni)
        acc[mi][ni] = __builtin_amdgcn_mfma_f32_16x16x32_bf16(af[mi], bfr[ni],
                                                              acc[mi][ni], 0, 0, 0);
  }
  const float* bias = pa.b[reg];
#pragma unroll
  for (int mi = 0; mi < 4; ++mi)
#pragma unroll
    for (int ni = 0; ni < 4; ++ni) {
      const int col = blockCol + wc + ni * 16 + lr;
      const float bv = bias[col];
#pragma unroll
      for (int r = 0; r < 4; ++r) {
        const int row = blockRow + wr + mi * 16 + lq * 4 + r;
        C[(size_t)row * 256 + col] = f2bf(acc[mi][ni][r] + bv);
      }
    }
}

// ---------------- aggregation: max TLP, barrier-free alphas -----------------
// Region (bid<8192): one (b,t), 4 dsts. Audio (bid>=8192): one node.
// Wave w == head w: dots via wredx, per-lane redundant softmax. !MEAN: no LDS,
// no barriers. MEAN: + head-mean/LN via dynamic LDS + slotted atomic pooling.
template <bool MEAN>
__global__ __launch_bounds__(256) void agg_kernel(
    const u16* __restrict__ h, const float* __restrict__ a_s,
    const float* __restrict__ a_d, const float* __restrict__ bias,
    const float* __restrict__ lng, const float* __restrict__ lnb,
    void* __restrict__ out) {
  extern __shared__ float dyn[];  // MEAN only: red[4096] + ls[32]
  const int tid = threadIdx.x;
  const int head = tid >> 6;
  const int c4 = tid * 4;
  const float4 sa = *(const float4*)(a_s + c4);
  const float4 da = *(const float4*)(a_d + c4);

  if (blockIdx.x < 8192) {
    // ---- region: bt = blockIdx.x ----
    const int bt = blockIdx.x;
    const int t = bt & 511;
    const bool hasPrev = t > 0;
    ushort4 rv[4], rp[4];
#pragma unroll
    for (int r = 0; r < 4; ++r)
      rv[r] = *(const ushort4*)(h + (size_t)(r * 8192 + bt) * 1024 + c4);
    if (hasPrev) {
#pragma unroll
      for (int r = 0; r < 4; ++r)
        rp[r] = *(const ushort4*)(h + (size_t)(r * 8192 + bt - 1) * 1024 + c4);
    }
    float4 hv[4], hp[4];
#pragma unroll
    for (int r = 0; r < 4; ++r) hv[r] = cvt4(rv[r]);
    float ss[4], dd[4], sp[4];
#pragma unroll
    for (int r = 0; r < 4; ++r) {
      ss[r] = wredx(dot4(hv[r], sa));
      dd[r] = wredx(dot4(hv[r], da));
    }
    if (hasPrev) {
#pragma unroll
      for (int r = 0; r < 4; ++r) hp[r] = cvt4(rp[r]);
#pragma unroll
      for (int r = 0; r < 4; ++r) sp[r] = wredx(dot4(hp[r], sa));
    }
    float4 av[4];
#pragma unroll
    for (int j = 0; j < 4; ++j) {
      const float ad = dd[j];
      float e0 = lrelu(ss[0] + ad), e1 = lrelu(ss[1] + ad);
      float e2 = lrelu(ss[2] + ad), e3 = lrelu(ss[3] + ad);
      float mx = fmaxf(fmaxf(e0, e1), fmaxf(e2, e3));
      float e4 = 0.f;
      if (hasPrev) { e4 = lrelu(sp[j] + ad); mx = fmaxf(mx, e4); }
      const float x0 = __expf(e0 - mx), x1 = __expf(e1 - mx);
      const float x2 = __expf(e2 - mx), x3 = __expf(e3 - mx);
      const float x4 = hasPrev ? __expf(e4 - mx) : 0.f;
      const float inv = 1.f / (x0 + x1 + x2 + x3 + x4 + 1e-16f);
      const float a0 = x0 * inv, a1 = x1 * inv, a2 = x2 * inv, a3 = x3 * inv;
      const float a4 = x4 * inv;
      float4 acc;
      acc.x = a0 * hv[0].x + a1 * hv[1].x + a2 * hv[2].x + a3 * hv[3].x;
      acc.y = a0 * hv[0].y + a1 * hv[1].y + a2 * hv[2].y + a3 * hv[3].y;
      acc.z = a0 * hv[0].z + a1 * hv[1].z + a2 * hv[2].z + a3 * hv[3].z;
      acc.w = a0 * hv[0].w + a1 * hv[1].w + a2 * hv[2].w + a3 * hv[3].w;
      if (hasPrev) {
        acc.x += a4 * hp[j].x; acc.y += a4 * hp[j].y;
        acc.z += a4 * hp[j].z; acc.w += a4 * hp[j].w;
      }
      av[j] = acc;
    }
    if constexpr (!MEAN) {
      const float4 bv = *(const float4*)(bias + c4);
      u16* ob = (u16*)out;
#pragma unroll
      for (int j = 0; j < 4; ++j) {
        ushort4 o;
        o.x = f2bf(av[j].x + bv.x); o.y = f2bf(av[j].y + bv.y);
        o.z = f2bf(av[j].z + bv.z); o.w = f2bf(av[j].w + bv.w);
        *(ushort4*)(ob + (size_t)(j * 8192 + bt) * 1024 + c4) = o;
      }
    } else {
      float* red = dyn;          // 4096
      float* ls = dyn + 4096;    // 32
#pragma unroll
      for (int j = 0; j < 4; ++j) *(float4*)(&red[j * 1024 + c4]) = av[j];
      __syncthreads();
      const float bb = bias[tid];
      float v[4];
#pragma unroll
      for (int j = 0; j < 4; ++j) {
        v[j] = 0.25f * (red[j * 1024 + tid] + red[j * 1024 + tid + 256] +
                        red[j * 1024 + tid + 512] + red[j * 1024 + tid + 768]) + bb;
        const float sj = wredx(v[j]);
        const float qj = wredx(v[j] * v[j]);
        if ((tid & 63) == 0) { ls[head * 8 + j * 2] = sj; ls[head * 8 + j * 2 + 1] = qj; }
      }
      __syncthreads();
      const int slot = bt & 7;
      float* po = (float*)out;
#pragma unroll
      for (int j = 0; j < 4; ++j) {
        const float S = ls[j * 2] + ls[8 + j * 2] + ls[16 + j * 2] + ls[24 + j * 2];
        const float Q = ls[j * 2 + 1] + ls[8 + j * 2 + 1] + ls[16 + j * 2 + 1] +
                        ls[24 + j * 2 + 1];
        const float mean = S * (1.f / 256.f);
        const float var = Q * (1.f / 256.f) - mean * mean;
        const float n = (v[j] - mean) * rsqrtf(var + 1e-5f) * lng[tid] + lnb[tid];
        const int ch = (j * 8192 + bt) / 3072;
        atomicAdd(po + (ch * 8 + slot) * 256 + tid, n);
      }
    }
  } else {
    // ---- audio: one node ----
    const int idx = blockIdx.x - 8192;  // b*1024 + ta
    const int ta = idx & 1023;
    const int node = 32768 + idx;
    const bool even = ((ta & 1) == 0);
    float4 v = cvt4(*(const ushort4*)(h + (size_t)node * 1024 + c4));
    if (even) {
      const int b = idx >> 10;
      const int tt = ta >> 1;
      const int le = 8192 + b * 512 + tt;
      const int re = 16384 + b * 512 + tt;
      float4 v1 = cvt4(*(const ushort4*)(h + (size_t)le * 1024 + c4));
      float4 v2 = cvt4(*(const ushort4*)(h + (size_t)re * 1024 + c4));
      const float s0 = wredx(dot4(v, sa));
      const float s1 = wredx(dot4(v1, sa));
      const float s2 = wredx(dot4(v2, sa));
      const float d0 = wredx(dot4(v, da));
      const float e0 = lrelu(s0 + d0), e1 = lrelu(s1 + d0), e2 = lrelu(s2 + d0);
      const float mx = fmaxf(e0, fmaxf(e1, e2));
      const float x0 = __expf(e0 - mx), x1 = __expf(e1 - mx), x2 = __expf(e2 - mx);
      const float inv = 1.f / (x0 + x1 + x2 + 1e-16f);
      const float a0 = x0 * inv, a1 = x1 * inv, a2 = x2 * inv;
      v.x = a0 * v.x + a1 * v1.x + a2 * v2.x;
      v.y = a0 * v.y + a1 * v1.y + a2 * v2.y;
      v.z = a0 * v.z + a1 * v1.z + a2 * v2.z;
      v.w = a0 * v.w + a1 * v1.w + a2 * v2.w;
    }
    if constexpr (!MEAN) {
      const float4 bv = *(const float4*)(bias + c4);
      ushort4 o;
      o.x = f2bf(v.x + bv.x); o.y = f2bf(v.y + bv.y);
      o.z = f2bf(v.z + bv.z); o.w = f2bf(v.w + bv.w);
      *(ushort4*)((u16*)out + (size_t)node * 1024 + c4) = o;
    } else {
      float* red = dyn;
      float* ls = dyn + 4096;
      *(float4*)(&red[c4]) = v;
      __syncthreads();
      float vA = 0.25f * (red[tid] + red[tid + 256] + red[tid + 512] +
                          red[tid + 768]) + bias[tid];
      const float sA = wredx(vA), qA = wredx(vA * vA);
      if ((tid & 63) == 0) { ls[head * 2] = sA; ls[head * 2 + 1] = qA; }
      __syncthreads();
      const float S = ls[0] + ls[2] + ls[4] + ls[6];
      const float Q = ls[1] + ls[3] + ls[5] + ls[7];
      const float mean = S * (1.f / 256.f);
      const float var = Q * (1.f / 256.f) - mean * mean;
      const float n = (vA - mean) * rsqrtf(var + 1e-5f) * lng[tid] + lnb[tid];
      const int ch = node / 3072;
      atomicAdd((float*)out + (ch * 8 + (idx & 7)) * 256 + tid, n);
    }
  }
}

// ---------------- partial-buffer zero + final reduce/scale ------------------
__global__ __launch_bounds__(256) void zero_kernel(float* __restrict__ p) {
  p[blockIdx.x * 256 + threadIdx.x] = 0.f;
}
__global__ __launch_bounds__(256) void finish_kernel(const float* __restrict__ part,
                                                     float* __restrict__ out) {
  const int chunk = blockIdx.x;
  const int c = threadIdx.x;
  float s = 0.f;
#pragma unroll
  for (int k = 0; k < 8; ++k) s += part[(chunk * 8 + k) * 256 + c];
  out[chunk * 256 + c] = s * (1.f / 3072.f);
}

// ---------------------------------------------------------------------------
extern "C" void kernel_launch(void* const* d_in, const int* in_sizes, int n_in,
                              void* d_out, int out_size, void* d_ws, size_t ws_size,
                              hipStream_t stream) {
  const float* x_reg[4] = {(const float*)d_in[0], (const float*)d_in[1],
                           (const float*)d_in[2], (const float*)d_in[3]};
  const float* audio = (const float*)d_in[4];
  const float* w_reg[4] = {(const float*)d_in[5], (const float*)d_in[7],
                           (const float*)d_in[9], (const float*)d_in[11]};
  const float* b_reg[4] = {(const float*)d_in[6], (const float*)d_in[8],
                           (const float*)d_in[10], (const float*)d_in[12]};
  const float* w_aud = (const float*)d_in[13];
  const float* b_aud = (const float*)d_in[14];
  const float* Wl[3] = {(const float*)d_in[15], (const float*)d_in[19],
                        (const float*)d_in[23]};
  const float* as_in[3] = {(const float*)d_in[16], (const float*)d_in[20],
                           (const float*)d_in[24]};
  const float* ad_in[3] = {(const float*)d_in[17], (const float*)d_in[21],
                           (const float*)d_in[25]};
  const float* bias_l[3] = {(const float*)d_in[18], (const float*)d_in[22],
                            (const float*)d_in[26]};
  const float* ln_g = (const float*)d_in[27];
  const float* ln_b = (const float*)d_in[28];

  // workspace layout (<200 MiB)
  char* ws = (char*)d_ws;
  u16* h_bf = (u16*)ws;                    // [N,1024] bf16 (96 MiB)
  u16* xb = (u16*)(ws + 100663296);        // [N,1024] bf16 x buffer
  u16* wt = (u16*)(ws + 201326592);        // packed bf16 weights (~5.8 MiB)
  float* part = (float*)(ws + 207355904);  // [16][8][256] pooling partials

  u16* wtp[5];
  for (int r = 0; r < 5; ++r) wtp[r] = wt + (size_t)r * 131072;
  u16* wt0 = wt + 655360;   // 512 frags
  u16* wt1 = wt + 917504;   // 2048 frags
  u16* wt2 = wt + 1966080;  // 2048 frags

  // 1) pack all weights into MFMA fragment order; zero pooling partials
  PK pk;
  for (int r = 0; r < 4; ++r) { pk.W[r] = w_reg[r]; pk.P[r] = wtp[r]; pk.KB[r] = 16; pk.NN[r] = 256; }
  pk.W[4] = w_aud; pk.P[4] = wtp[4]; pk.KB[4] = 16; pk.NN[4] = 256;
  pk.W[5] = Wl[0]; pk.P[5] = wt0; pk.KB[5] = 8;  pk.NN[5] = 1024;
  pk.W[6] = Wl[1]; pk.P[6] = wt1; pk.KB[6] = 32; pk.NN[6] = 1024;
  pk.W[7] = Wl[2]; pk.P[7] = wt2; pk.KB[7] = 32; pk.NN[7] = 1024;
  pk.st[0] = 0;
  {
    const int nfr[8] = {256, 256, 256, 256, 256, 512, 2048, 2048};
    int acc = 0;
    for (int e = 0; e < 8; ++e) { acc += nfr[e]; pk.st[e + 1] = acc; }
  }
  pack_kernel<<<pk.st[8] / 4, 256, 0, stream>>>(pk);
  zero_kernel<<<128, 256, 0, stream>>>(part);

  // 2) fused input projections (fp32 in, bf16 out) -> x0 [N,256]
  ProjArgs pa;
  for (int r = 0; r < 4; ++r) { pa.x[r] = x_reg[r]; pa.w[r] = wtp[r]; pa.b[r] = b_reg[r]; }
  pa.x[4] = audio; pa.w[4] = wtp[4]; pa.b[4] = b_aud;
  proj_kernel<<<dim3(2, 384), 256, 0, stream>>>(pa, xb);

  // 3) three GAT layers: BK=64 dbuf gemm -> max-TLP barrier-free agg
  const u16* wl[3] = {wt0, wt1, wt2};
  const int Kl[3] = {256, 1024, 1024};
  const size_t dynLds = (4096 + 32) * sizeof(float);
  for (int l = 0; l < 3; ++l) {
    gemm_kernel<<<dim3(8, 384), 256, 0, stream>>>(xb, wl[l], h_bf, Kl[l], 1024);
    if (l < 2)
      agg_kernel<false><<<24576, 256, 0, stream>>>(h_bf, as_in[l], ad_in[l],
                                                   bias_l[l], nullptr, nullptr, xb);
    else
      agg_kernel<true><<<24576, 256, dynLds, stream>>>(h_bf, as_in[l], ad_in[l],
                                                       bias_l[l], ln_g, ln_b, part);
  }

  // 4) final reduce: out[chunk][c] = sum_slots / 3072
  finish_kernel<<<16, 256, 0, stream>>>(part, (float*)d_out);
}

// Round 11
// 616.859 us; speedup vs baseline: 1.1521x; 1.1186x over previous
//
#include <hip/hip_runtime.h>

// ---------------------------------------------------------------------------
// MultiModalRelationGraph — R11  (R7 + audio-merged agg blocks)
// - GEMM (R7): BK=64 ping-pong LDS A via global_load_lds(16B), fragment-packed
//   B global->VGPR, XCD swizzle, XOR LDS swizzle. ~860 TF (m97-family plateau).
// - Agg ledger: R7 one-(b,t)-per-block + wred/LDS softmax = 95us local optimum.
//   Strip-mining (R8:131, R9:152) kills TLP; redundant per-lane softmax +
//   per-node atomics (R10) adds VALU/atomic floods. R11 keeps the R7 scheme
//   and merges audio nodes into region blocks: block (b,t) handles 4 region
//   dsts + audio(b,2t) (reuses the eye rows/dots already loaded!) + audio
//   (b,2t+1) passthrough. Kills 16384 blocks + duplicate eye loads/dots.
// - MEAN layer: R7's proven path (xf fp32 -> ln_pool -> pool2), no atomics.
// Node layout: region i in [i*8192,(i+1)*8192), node = i*8192 + b*512 + t.
// Audio: 32768 + b*1024 + ta.
// ---------------------------------------------------------------------------

typedef unsigned short u16;
typedef unsigned int u32;
typedef __bf16 bf16x8 __attribute__((ext_vector_type(8)));
typedef float f32x4 __attribute__((ext_vector_type(4)));

#define ASYNC16(gp, lp)                                                        \
  __builtin_amdgcn_global_load_lds(                                            \
      (const __attribute__((address_space(1))) void*)(gp),                     \
      (__attribute__((address_space(3))) void*)(lp), 16, 0, 0)

__device__ __forceinline__ u16 f2bf(float f) {
  union { float f; u32 u; } v; v.f = f;
  u32 u = v.u + 0x7FFFu + ((v.u >> 16) & 1u);  // RNE
  return (u16)(u >> 16);
}
__device__ __forceinline__ float bf2f(u16 x) {
  union { u32 u; float f; } v; v.u = ((u32)x) << 16;
  return v.f;
}
__device__ __forceinline__ float4 load_bf4(const u16* p) {
  ushort4 s = *(const ushort4*)p;
  float4 r; r.x = bf2f(s.x); r.y = bf2f(s.y); r.z = bf2f(s.z); r.w = bf2f(s.w);
  return r;
}
__device__ __forceinline__ float lrelu(float v) { return v > 0.f ? v : 0.2f * v; }
__device__ __forceinline__ float dot4(float4 a, float4 b) {
  return a.x * b.x + a.y * b.y + a.z * b.z + a.w * b.w;
}
__device__ __forceinline__ float wred(float v) {  // lane 0 valid
#pragma unroll
  for (int off = 32; off; off >>= 1) v += __shfl_down(v, off);
  return v;
}
__device__ __forceinline__ float wredx(float v) {  // all lanes valid
#pragma unroll
  for (int off = 32; off; off >>= 1) v += __shfl_xor(v, off);
  return v;
}

// ---------------- weight pack: W [K][N] fp32 -> MFMA B-fragment order -------
struct PK { const float* W[8]; u16* P[8]; int KB[8]; int NN[8]; int st[9]; };
__global__ __launch_bounds__(256) void pack_kernel(PK p) {
  const int f = blockIdx.x * 4 + (threadIdx.x >> 6);
  const int lane = threadIdx.x & 63;
  int e = 0;
  while (f >= p.st[e + 1]) ++e;
  const int local = f - p.st[e];
  const int KB = p.KB[e], N = p.NN[e];
  const int nt = local / KB, kb = local % KB;
  const float* W = p.W[e] + (size_t)(kb * 32 + (lane >> 4) * 8) * N + nt * 16 + (lane & 15);
  u16* dst = p.P[e] + ((size_t)local * 64 + lane) * 8;
  u16 o[8];
#pragma unroll
  for (int j = 0; j < 8; ++j) o[j] = f2bf(W[(size_t)j * N]);
  *(uint4*)dst = *(uint4*)o;
}

// ---------------- layer GEMM: C[M,N]=A[M,K]@W^T; BK=64 dbuf LDS A (R7) ------
__global__ __launch_bounds__(256) void gemm_kernel(
    const u16* __restrict__ A, const u16* __restrict__ Bp, u16* __restrict__ C,
    int K, int ldc) {
  __shared__ __align__(16) u16 As[2][2][128 * 32];
  const int KB = K >> 5;
  const int KB2 = K >> 6;
  const int w = blockIdx.y * 8 + blockIdx.x;
  const int xcd = w & 7, m = w >> 3;
  const int blockCol = (m & 7) * 128;
  const int blockRow = ((m >> 3) * 8 + xcd) * 128;
  const int tid = threadIdx.x;
  const int wave = tid >> 6, lane = tid & 63;
  const int wr = (wave >> 1) * 64, wc = (wave & 1) * 64;
  const int lr = lane & 15, lq = lane >> 4;
  const int sRow = wave * 16 + (lane >> 2);
  const int sGc = (lane & 3) ^ ((sRow >> 1) & 3);
  const size_t aOff0 = (size_t)(blockRow + sRow) * K + sGc * 8;
  const size_t aOff1 = aOff0 + (size_t)64 * K;
  const int ldsOff0 = wave * 512;
  const int ldsOff1 = 2048 + wave * 512;

  const u16* Bn[4];
#pragma unroll
  for (int ni = 0; ni < 4; ++ni)
    Bn[ni] = Bp + ((size_t)(((blockCol + wc) >> 4) + ni) * KB) * 512 + lane * 8;

  f32x4 acc[4][4] = {};

#pragma unroll
  for (int h = 0; h < 2; ++h) {
    ASYNC16(A + aOff0 + h * 32, As[0][h] + ldsOff0);
    ASYNC16(A + aOff1 + h * 32, As[0][h] + ldsOff1);
  }
  __syncthreads();

  for (int kb2 = 0; kb2 < KB2; ++kb2) {
    const int cb = kb2 & 1;
    if (kb2 + 1 < KB2) {
      const size_t k1 = (size_t)(kb2 + 1) * 64;
#pragma unroll
      for (int h = 0; h < 2; ++h) {
        ASYNC16(A + aOff0 + k1 + h * 32, As[cb ^ 1][h] + ldsOff0);
        ASYNC16(A + aOff1 + k1 + h * 32, As[cb ^ 1][h] + ldsOff1);
      }
    }
#pragma unroll
    for (int h = 0; h < 2; ++h) {
      const int kb = kb2 * 2 + h;
      const u16* cur = As[cb][h];
      bf16x8 bfr[4];
#pragma unroll
      for (int ni = 0; ni < 4; ++ni)
        bfr[ni] = *(const bf16x8*)(Bn[ni] + (size_t)kb * 512);
      bf16x8 af[4];
#pragma unroll
      for (int mi = 0; mi < 4; ++mi) {
        const int R = wr + mi * 16 + lr;
        const int cp = lq ^ ((R >> 1) & 3);
        af[mi] = *(const bf16x8*)(cur + R * 32 + cp * 8);
      }
#pragma unroll
      for (int mi = 0; mi < 4; ++mi)
#pragma unroll
        for (int ni = 0; ni < 4; ++ni)
          acc[mi][ni] = __builtin_amdgcn_mfma_f32_16x16x32_bf16(af[mi], bfr[ni],
                                                                acc[mi][ni], 0, 0, 0);
    }
    __syncthreads();
  }
#pragma unroll
  for (int mi = 0; mi < 4; ++mi)
#pragma unroll
    for (int ni = 0; ni < 4; ++ni) {
      const int col = blockCol + wc + ni * 16 + lr;
#pragma unroll
      for (int r = 0; r < 4; ++r) {
        const int row = blockRow + wr + mi * 16 + lq * 4 + r;
        C[(size_t)row * ldc + col] = f2bf(acc[mi][ni][r]);
      }
    }
}

// ---------------- fused input projection (fp32 A in-register cvt) -----------
struct ProjArgs { const float* x[5]; const u16* w[5]; const float* b[5]; };
__global__ __launch_bounds__(256) void proj_kernel(ProjArgs pa,
                                                   u16* __restrict__ C) {
  __shared__ __align__(16) u16 As[128 * 32];
  const int blockRow = blockIdx.y * 128, blockCol = blockIdx.x * 128;
  const int reg = blockRow >= 32768 ? 4 : (blockRow >> 13);
  const int regBase = reg == 4 ? 32768 : reg * 8192;
  const float* Af = pa.x[reg] + (size_t)(blockRow - regBase) * 512;
  const u16* Bp = pa.w[reg];
  const int tid = threadIdx.x;
  const int wave = tid >> 6, lane = tid & 63;
  const int wr = (wave >> 1) * 64, wc = (wave & 1) * 64;
  const int lr = lane & 15, lq = lane >> 4;
  const int rr = tid >> 2;
  const int cphys = tid & 3;
  const int sGc = cphys ^ ((tid >> 3) & 3);

  const u16* Bn[4];
#pragma unroll
  for (int ni = 0; ni < 4; ++ni)
    Bn[ni] = Bp + ((size_t)(((blockCol + wc) >> 4) + ni) * 16) * 512 + lane * 8;

  f32x4 acc[4][4] = {};

  for (int k0 = 0; k0 < 512; k0 += 32) {
    __syncthreads();
    bf16x8 bfr[4];
#pragma unroll
    for (int ni = 0; ni < 4; ++ni)
      bfr[ni] = *(const bf16x8*)(Bn[ni] + (size_t)k0 * 16);
#pragma unroll
    for (int i = 0; i < 2; ++i) {
      const int row = i * 64 + rr;
      const float* ap = Af + (size_t)row * 512 + k0 + sGc * 8;
      float4 f0 = *(const float4*)(ap);
      float4 f1 = *(const float4*)(ap + 4);
      uint4 pk;
      pk.x = (u32)f2bf(f0.x) | ((u32)f2bf(f0.y) << 16);
      pk.y = (u32)f2bf(f0.z) | ((u32)f2bf(f0.w) << 16);
      pk.z = (u32)f2bf(f1.x) | ((u32)f2bf(f1.y) << 16);
      pk.w = (u32)f2bf(f1.z) | ((u32)f2bf(f1.w) << 16);
      *(uint4*)(&As[row * 32 + cphys * 8]) = pk;
    }
    __syncthreads();
    bf16x8 af[4];
#pragma unroll
    for (int mi = 0; mi < 4; ++mi) {
      const int R = wr + mi * 16 + lr;
      const int cp = lq ^ ((R >> 1) & 3);
      af[mi] = *(const bf16x8*)(&As[R * 32 + cp * 8]);
    }
#pragma unroll
    for (int mi = 0; mi < 4; ++mi)
#pragma unroll
      for (int ni = 0; ni < 4; ++ni)
        acc[mi][ni] = __builtin_amdgcn_mfma_f32_16x16x32_bf16(af[mi], bfr[ni],
                                                              acc[mi][ni], 0, 0, 0);
  }
  const float* bias = pa.b[reg];
#pragma unroll
  for (int mi = 0; mi < 4; ++mi)
#pragma unroll
    for (int ni = 0; ni < 4; ++ni) {
      const int col = blockCol + wc + ni * 16 + lr;
      const float bv = bias[col];
#pragma unroll
      for (int r = 0; r < 4; ++r) {
        const int row = blockRow + wr + mi * 16 + lq * 4 + r;
        C[(size_t)row * 256 + col] = f2bf(acc[mi][ni][r] + bv);
      }
    }
}

// ---------------- merged aggregation: block (b,t) -> 6 dst nodes ------------
// dsts: 4 regions at (b,t), audio(b,2t) (srcs: self + eye rows 1,2 already
// loaded), audio(b,2t+1) (self-loop passthrough). R7 softmax scheme:
// wred dots (lane0) -> LDS -> 20-thread softmax -> LDS -> combine.
// MEAN: head-mean -> xf fp32 (LN+pool in separate proven kernels).
template <bool MEAN>
__global__ __launch_bounds__(256) void agg_kernel(
    const u16* __restrict__ h, const float* __restrict__ a_s,
    const float* __restrict__ a_d, const float* __restrict__ bias,
    void* __restrict__ out) {
  extern __shared__ float red[];  // MEAN only: [6][1024]
  const int tid = threadIdx.x;
  const int head = tid >> 6, lane = tid & 63;
  const int c4 = tid * 4;
  const float4 sa = *(const float4*)(a_s + c4);
  const float4 da = *(const float4*)(a_d + c4);
  __shared__ float asL[4][4], adL[4][4], apL[4][4], aeS[4], aeD[4];
  __shared__ float alpha[4][4][5], alphaA[4][3];

  const int bt = blockIdx.x;
  const int b = bt >> 9, t = bt & 511;
  const bool hasPrev = t > 0;
  const int nodeE = 32768 + b * 1024 + 2 * t;  // audio even
  const int nodeO = nodeE + 1;                 // audio odd

  float4 hv[4], hp[4];
#pragma unroll
  for (int r = 0; r < 4; ++r)
    hv[r] = load_bf4(h + (size_t)(r * 8192 + bt) * 1024 + c4);
  float4 hae = load_bf4(h + (size_t)nodeE * 1024 + c4);
  float4 hao = load_bf4(h + (size_t)nodeO * 1024 + c4);
  if (hasPrev) {
#pragma unroll
    for (int r = 0; r < 4; ++r)
      hp[r] = load_bf4(h + (size_t)(r * 8192 + bt - 1) * 1024 + c4);
  }
  // dots (wave w == head w); lane0-valid wred, stash to LDS
#pragma unroll
  for (int r = 0; r < 4; ++r) {
    float ss = wred(dot4(hv[r], sa));
    float dd = wred(dot4(hv[r], da));
    float sp = hasPrev ? wred(dot4(hp[r], sa)) : 0.f;
    if (lane == 0) { asL[r][head] = ss; adL[r][head] = dd; apL[r][head] = sp; }
  }
  {
    float se = wred(dot4(hae, sa));
    float de = wred(dot4(hae, da));
    if (lane == 0) { aeS[head] = se; aeD[head] = de; }
  }
  __syncthreads();
  if (tid < 16) {
    const int j = tid >> 2, hh = tid & 3;
    const float ad = adL[j][hh];
    float e[5];
#pragma unroll
    for (int r = 0; r < 4; ++r) e[r] = lrelu(asL[r][hh] + ad);
    int cnt = 4;
    if (hasPrev) { e[4] = lrelu(apL[j][hh] + ad); cnt = 5; }
    float mx = e[0];
    for (int k = 1; k < cnt; ++k) mx = fmaxf(mx, e[k]);
    float s = 0.f, ex[5];
    for (int k = 0; k < cnt; ++k) { ex[k] = __expf(e[k] - mx); s += ex[k]; }
    const float inv = 1.f / (s + 1e-16f);
#pragma unroll
    for (int k = 0; k < 5; ++k) alpha[j][hh][k] = (k < cnt) ? ex[k] * inv : 0.f;
  } else if (tid < 20) {
    const int hh = tid - 16;  // audio-even softmax: {self, left eye, right eye}
    const float ad = aeD[hh];
    const float e0 = lrelu(aeS[hh] + ad);
    const float e1 = lrelu(asL[1][hh] + ad);
    const float e2 = lrelu(asL[2][hh] + ad);
    const float mx = fmaxf(e0, fmaxf(e1, e2));
    const float x0 = __expf(e0 - mx), x1 = __expf(e1 - mx), x2 = __expf(e2 - mx);
    const float inv = 1.f / (x0 + x1 + x2 + 1e-16f);
    alphaA[hh][0] = x0 * inv; alphaA[hh][1] = x1 * inv; alphaA[hh][2] = x2 * inv;
  }
  __syncthreads();

  float4 av[6];
#pragma unroll
  for (int j = 0; j < 4; ++j) {
    const float* al = &alpha[j][head][0];
    float4 acc;
    acc.x = al[0] * hv[0].x + al[1] * hv[1].x + al[2] * hv[2].x + al[3] * hv[3].x;
    acc.y = al[0] * hv[0].y + al[1] * hv[1].y + al[2] * hv[2].y + al[3] * hv[3].y;
    acc.z = al[0] * hv[0].z + al[1] * hv[1].z + al[2] * hv[2].z + al[3] * hv[3].z;
    acc.w = al[0] * hv[0].w + al[1] * hv[1].w + al[2] * hv[2].w + al[3] * hv[3].w;
    if (hasPrev) {
      const float a4 = al[4];
      acc.x += a4 * hp[j].x; acc.y += a4 * hp[j].y;
      acc.z += a4 * hp[j].z; acc.w += a4 * hp[j].w;
    }
    av[j] = acc;
  }
  {
    const float a0 = alphaA[head][0], a1 = alphaA[head][1], a2 = alphaA[head][2];
    float4 acc;
    acc.x = a0 * hae.x + a1 * hv[1].x + a2 * hv[2].x;
    acc.y = a0 * hae.y + a1 * hv[1].y + a2 * hv[2].y;
    acc.z = a0 * hae.z + a1 * hv[1].z + a2 * hv[2].z;
    acc.w = a0 * hae.w + a1 * hv[1].w + a2 * hv[2].w;
    av[4] = acc;
    av[5] = hao;  // odd audio: self-loop only
  }

  if constexpr (!MEAN) {
    const float4 bv = *(const float4*)(bias + c4);
    u16* ob = (u16*)out;
    size_t rows[6];
#pragma unroll
    for (int j = 0; j < 4; ++j) rows[j] = (size_t)(j * 8192 + bt);
    rows[4] = (size_t)nodeE; rows[5] = (size_t)nodeO;
#pragma unroll
    for (int k = 0; k < 6; ++k) {
      ushort4 o;
      o.x = f2bf(av[k].x + bv.x); o.y = f2bf(av[k].y + bv.y);
      o.z = f2bf(av[k].z + bv.z); o.w = f2bf(av[k].w + bv.w);
      *(ushort4*)(ob + rows[k] * 1024 + c4) = o;
    }
  } else {
#pragma unroll
    for (int k = 0; k < 6; ++k) *(float4*)(&red[k * 1024 + c4]) = av[k];
    __syncthreads();
    const float bb = bias[tid];
    float* of = (float*)out;
    size_t rows[6];
#pragma unroll
    for (int j = 0; j < 4; ++j) rows[j] = (size_t)(j * 8192 + bt);
    rows[4] = (size_t)nodeE; rows[5] = (size_t)nodeO;
#pragma unroll
    for (int k = 0; k < 6; ++k) {
      const float v = 0.25f * (red[k * 1024 + tid] + red[k * 1024 + tid + 256] +
                               red[k * 1024 + tid + 512] + red[k * 1024 + tid + 768]) + bb;
      of[rows[k] * 256 + tid] = v;
    }
  }
}

// ---------------- barrier-free LayerNorm(256) + partial pooling (R7) --------
__global__ __launch_bounds__(256) void ln_pool_kernel(
    const float* __restrict__ xf, const float* __restrict__ g,
    const float* __restrict__ bb, float* __restrict__ part) {
  const int tid = threadIdx.x;
  const int wave = tid >> 6, lane = tid & 63;
  const int node0 = blockIdx.x * 64 + wave * 16;
  const float4 g4 = *(const float4*)(g + lane * 4);
  const float4 b4 = *(const float4*)(bb + lane * 4);
  float4 acc = {0.f, 0.f, 0.f, 0.f};
  for (int i = 0; i < 16; ++i) {
    const float4 v = *(const float4*)(xf + (size_t)(node0 + i) * 256 + lane * 4);
    const float s = wredx(v.x + v.y + v.z + v.w);
    const float q = wredx(v.x * v.x + v.y * v.y + v.z * v.z + v.w * v.w);
    const float mean = s * (1.f / 256.f);
    const float var = q * (1.f / 256.f) - mean * mean;
    const float rstd = rsqrtf(var + 1e-5f);
    acc.x += (v.x - mean) * rstd * g4.x + b4.x;
    acc.y += (v.y - mean) * rstd * g4.y + b4.y;
    acc.z += (v.z - mean) * rstd * g4.z + b4.z;
    acc.w += (v.w - mean) * rstd * g4.w + b4.w;
  }
  *(float4*)(part + (size_t)(blockIdx.x * 4 + wave) * 256 + lane * 4) = acc;
}

__global__ __launch_bounds__(256) void pool2_kernel(const float* __restrict__ part,
                                                    float* __restrict__ out) {
  const int chunk = blockIdx.x;
  const int c = threadIdx.x;
  float s = 0.f;
  for (int i = 0; i < 192; ++i) s += part[(size_t)(chunk * 192 + i) * 256 + c];
  out[chunk * 256 + c] = s * (1.f / 3072.f);
}

// ---------------------------------------------------------------------------
extern "C" void kernel_launch(void* const* d_in, const int* in_sizes, int n_in,
                              void* d_out, int out_size, void* d_ws, size_t ws_size,
                              hipStream_t stream) {
  const float* x_reg[4] = {(const float*)d_in[0], (const float*)d_in[1],
                           (const float*)d_in[2], (const float*)d_in[3]};
  const float* audio = (const float*)d_in[4];
  const float* w_reg[4] = {(const float*)d_in[5], (const float*)d_in[7],
                           (const float*)d_in[9], (const float*)d_in[11]};
  const float* b_reg[4] = {(const float*)d_in[6], (const float*)d_in[8],
                           (const float*)d_in[10], (const float*)d_in[12]};
  const float* w_aud = (const float*)d_in[13];
  const float* b_aud = (const float*)d_in[14];
  const float* Wl[3] = {(const float*)d_in[15], (const float*)d_in[19],
                        (const float*)d_in[23]};
  const float* as_in[3] = {(const float*)d_in[16], (const float*)d_in[20],
                           (const float*)d_in[24]};
  const float* ad_in[3] = {(const float*)d_in[17], (const float*)d_in[21],
                           (const float*)d_in[25]};
  const float* bias_l[3] = {(const float*)d_in[18], (const float*)d_in[22],
                            (const float*)d_in[26]};
  const float* ln_g = (const float*)d_in[27];
  const float* ln_b = (const float*)d_in[28];

  // workspace layout (<200 MiB)
  char* ws = (char*)d_ws;
  u16* h_bf = (u16*)ws;                    // [N,1024] bf16 (96 MiB)
  float* part = (float*)ws;                // ln partials (h dead by then)
  u16* xb = (u16*)(ws + 100663296);        // [N,1024] bf16 x buffer
  float* xf = (float*)xb;                  // layer-2 output [N,256] fp32
  u16* wt = (u16*)(ws + 201326592);        // packed bf16 weights (~5.8 MiB)

  u16* wtp[5];
  for (int r = 0; r < 5; ++r) wtp[r] = wt + (size_t)r * 131072;
  u16* wt0 = wt + 655360;   // 512 frags
  u16* wt1 = wt + 917504;   // 2048 frags
  u16* wt2 = wt + 1966080;  // 2048 frags

  // 1) pack all weights into MFMA fragment order
  PK pk;
  for (int r = 0; r < 4; ++r) { pk.W[r] = w_reg[r]; pk.P[r] = wtp[r]; pk.KB[r] = 16; pk.NN[r] = 256; }
  pk.W[4] = w_aud; pk.P[4] = wtp[4]; pk.KB[4] = 16; pk.NN[4] = 256;
  pk.W[5] = Wl[0]; pk.P[5] = wt0; pk.KB[5] = 8;  pk.NN[5] = 1024;
  pk.W[6] = Wl[1]; pk.P[6] = wt1; pk.KB[6] = 32; pk.NN[6] = 1024;
  pk.W[7] = Wl[2]; pk.P[7] = wt2; pk.KB[7] = 32; pk.NN[7] = 1024;
  pk.st[0] = 0;
  {
    const int nfr[8] = {256, 256, 256, 256, 256, 512, 2048, 2048};
    int acc = 0;
    for (int e = 0; e < 8; ++e) { acc += nfr[e]; pk.st[e + 1] = acc; }
  }
  pack_kernel<<<pk.st[8] / 4, 256, 0, stream>>>(pk);

  // 2) fused input projections (fp32 in, bf16 out) -> x0 [N,256]
  ProjArgs pa;
  for (int r = 0; r < 4; ++r) { pa.x[r] = x_reg[r]; pa.w[r] = wtp[r]; pa.b[r] = b_reg[r]; }
  pa.x[4] = audio; pa.w[4] = wtp[4]; pa.b[4] = b_aud;
  proj_kernel<<<dim3(2, 384), 256, 0, stream>>>(pa, xb);

  // 3) three GAT layers: BK=64 dbuf gemm -> merged agg (8192 blocks)
  const u16* wl[3] = {wt0, wt1, wt2};
  const int Kl[3] = {256, 1024, 1024};
  const size_t dynLds = 6 * 1024 * sizeof(float);
  for (int l = 0; l < 3; ++l) {
    gemm_kernel<<<dim3(8, 384), 256, 0, stream>>>(xb, wl[l], h_bf, Kl[l], 1024);
    if (l < 2)
      agg_kernel<false><<<8192, 256, 0, stream>>>(h_bf, as_in[l], ad_in[l],
                                                  bias_l[l], xb);
    else
      agg_kernel<true><<<8192, 256, dynLds, stream>>>(h_bf, as_in[l], ad_in[l],
                                                      bias_l[l], xf);
  }

  // 4) LayerNorm + chunk pooling -> out [16,256]
  ln_pool_kernel<<<768, 256, 0, stream>>>(xf, ln_g, ln_b, part);
  pool2_kernel<<<16, 256, 0, stream>>>(part, (float*)d_out);
}